// Round 1
// baseline (922.691 us; speedup 1.0000x reference)
//
#include <hip/hip_runtime.h>
#include <stdint.h>

typedef unsigned int u32;
typedef unsigned long long u64;

#define B_ 16
#define N_ 200000
#define PRE 4096
#define POST 2000

// ---------------- histogram pass 1: bits [31:20] ----------------
__global__ __launch_bounds__(256) void k_hist1(const float* __restrict__ scores,
                                               u32* __restrict__ hist) {
  int b = blockIdx.y;
  __shared__ u32 h[4096];
  for (int i = threadIdx.x; i < 4096; i += blockDim.x) h[i] = 0;
  __syncthreads();
  const float* s = scores + (size_t)b * N_;
  for (int i = blockIdx.x * blockDim.x + threadIdx.x; i < N_;
       i += gridDim.x * blockDim.x) {
    u32 u = __float_as_uint(s[i]);
    atomicAdd(&h[u >> 20], 1u);
  }
  __syncthreads();
  u32* g = hist + (size_t)b * 4096;
  for (int i = threadIdx.x; i < 4096; i += blockDim.x) {
    u32 v = h[i];
    if (v) atomicAdd(&g[i], v);
  }
}

// ---------------- histogram pass 2: filter top12, bits [19:8] ----------------
__global__ __launch_bounds__(256) void k_hist2(const float* __restrict__ scores,
                                               const u32* __restrict__ pref,
                                               u32* __restrict__ hist) {
  int b = blockIdx.y;
  u32 P = pref[b];
  const float* s = scores + (size_t)b * N_;
  u32* g = hist + (size_t)b * 4096;
  for (int i = blockIdx.x * blockDim.x + threadIdx.x; i < N_;
       i += gridDim.x * blockDim.x) {
    u32 u = __float_as_uint(s[i]);
    if ((u & 0xFFF00000u) == P) atomicAdd(&g[(u >> 8) & 0xFFFu], 1u);
  }
}

// ---------------- histogram pass 3: filter top24, bits [7:0] ----------------
__global__ __launch_bounds__(256) void k_hist3(const float* __restrict__ scores,
                                               const u32* __restrict__ pref,
                                               u32* __restrict__ hist) {
  int b = blockIdx.y;
  u32 P = pref[b];
  const float* s = scores + (size_t)b * N_;
  u32* g = hist + (size_t)b * 256;
  for (int i = blockIdx.x * blockDim.x + threadIdx.x; i < N_;
       i += gridDim.x * blockDim.x) {
    u32 u = __float_as_uint(s[i]);
    if ((u & 0xFFFFFF00u) == P) atomicAdd(&g[u & 0xFFu], 1u);
  }
}

// ---------------- threshold finder (generic, 64 threads = 1 wave) -----------
__global__ __launch_bounds__(64) void k_thresh(const u32* __restrict__ hist,
                                               int nbins, int shift,
                                               u32* __restrict__ pref,
                                               u32* __restrict__ K) {
  int b = blockIdx.x;
  int t = threadIdx.x;
  const u32* h = hist + (size_t)b * nbins;
  int C = nbins >> 6;
  int base = t * C;
  u32 s = 0;
  for (int j = 0; j < C; ++j) s += h[base + j];
  u32 suf = s;  // inclusive suffix sum over lanes
#pragma unroll
  for (int off = 1; off < 64; off <<= 1) {
    u32 v = __shfl_down(suf, off);
    if (t + off < 64) suf += v;
  }
  u32 Kin = K[b];
  if (Kin == 0) Kin = PRE;  // memset-zeroed sentinel on first pass
  bool cond = (suf >= Kin) && (suf - s < Kin);
  if (cond) {
    u32 cum = suf - s;  // count strictly above my chunk
    for (int v = C - 1; v >= 0; --v) {
      u32 hv = h[base + v];
      cum += hv;
      if (cum >= Kin) {
        pref[b] |= ((u32)(base + v)) << shift;
        K[b] = Kin - (cum - hv);
        break;
      }
    }
  }
}

// ---------------- selection: >S* into sel, ==S* into eq buffer --------------
__global__ __launch_bounds__(256) void k_select(const float* __restrict__ scores,
                                                const u32* __restrict__ pref,
                                                u32* __restrict__ cnt_gt,
                                                u32* __restrict__ cnt_eq,
                                                u64* __restrict__ sel,
                                                u32* __restrict__ eqbuf) {
  int b = blockIdx.y;
  u32 S = pref[b];
  const float* s = scores + (size_t)b * N_;
  for (int i = blockIdx.x * blockDim.x + threadIdx.x; i < N_;
       i += gridDim.x * blockDim.x) {
    u32 u = __float_as_uint(s[i]);
    if (u > S) {
      u32 p = atomicAdd(&cnt_gt[b], 1u);
      if (p < PRE) sel[(size_t)b * PRE + p] = ((u64)u << 32) | (u32)(~(u32)i);
    } else if (u == S) {
      u32 p = atomicAdd(&cnt_eq[b], 1u);
      if (p < PRE) eqbuf[(size_t)b * PRE + p] = (u32)i;
    }
  }
}

// ---------------- tie resolve: smallest Kf indices among equals -------------
__global__ __launch_bounds__(256) void k_tie(const u32* __restrict__ pref,
                                             const u32* __restrict__ K,
                                             const u32* __restrict__ cnt_eq,
                                             const u32* __restrict__ eqbuf,
                                             u64* __restrict__ sel) {
  int b = blockIdx.x;
  u32 Kf = K[b];
  u32 ne = cnt_eq[b];
  if (ne > PRE) ne = PRE;
  u32 S = pref[b];
  u32 basep = PRE - Kf;
  const u32* eq = eqbuf + (size_t)b * PRE;
  for (u32 p = threadIdx.x; p < ne; p += blockDim.x) {
    u32 my = eq[p];
    u32 rank = 0;
    for (u32 q = 0; q < ne; ++q) rank += (eq[q] < my) ? 1u : 0u;
    if (rank < Kf)
      sel[(size_t)b * PRE + basep + rank] = ((u64)S << 32) | (u32)(~my);
  }
}

// ---------------- bitonic sort of 4096 keys (descending), per batch ---------
__global__ __launch_bounds__(1024) void k_sort(const u64* __restrict__ sel,
                                               u32* __restrict__ sidx,
                                               float* __restrict__ sscore) {
  __shared__ u64 k[PRE];
  int b = blockIdx.x, t = threadIdx.x;
  for (int i = t; i < PRE; i += 1024) k[i] = sel[(size_t)b * PRE + i];
  __syncthreads();
  for (int kk = 2; kk <= PRE; kk <<= 1) {
    for (int j = kk >> 1; j > 0; j >>= 1) {
      for (int i = t; i < PRE; i += 1024) {
        int ixj = i ^ j;
        if (ixj > i) {
          u64 a = k[i], bv = k[ixj];
          bool up = (i & kk) == 0;
          if (up ? (a < bv) : (a > bv)) {
            k[i] = bv;
            k[ixj] = a;
          }
        }
      }
      __syncthreads();
    }
  }
  for (int i = t; i < PRE; i += 1024) {
    u64 key = k[i];
    sidx[(size_t)b * PRE + i] = ~(u32)key;
    sscore[(size_t)b * PRE + i] = __uint_as_float((u32)(key >> 32));
  }
}

// ---------------- gather topk boxes ----------------
__global__ __launch_bounds__(256) void k_gather(const float4* __restrict__ boxes,
                                                const u32* __restrict__ sidx,
                                                float4* __restrict__ tb) {
  int b = blockIdx.y;
  int i = blockIdx.x * blockDim.x + threadIdx.x;
  if (i >= PRE) return;
  u32 idx = sidx[(size_t)b * PRE + i];
  tb[(size_t)b * PRE + i] = boxes[(size_t)b * N_ + idx];
}

// ---------------- NMS pairwise mask (64x64 tiles) ----------------
__global__ __launch_bounds__(64) void k_mask(const float4* __restrict__ tb,
                                             u64* __restrict__ mask) {
  int cb = blockIdx.x, rb = blockIdx.y, b = blockIdx.z;
  int t = threadIdx.x;
  int i = rb * 64 + t;
  if (cb < rb) {  // all column indices < row indices: no suppression bits
    mask[((size_t)b * PRE + i) * 64 + cb] = 0ull;
    return;
  }
  __shared__ float4 cbox[64];
  __shared__ float carea[64];
  float4 cj = tb[(size_t)b * PRE + cb * 64 + t];
  cbox[t] = cj;
  carea[t] = (cj.z - cj.x) * (cj.w - cj.y);  // (y2-y1)*(x2-x1)
  __syncthreads();
  float4 bi = tb[(size_t)b * PRE + i];
  float bar = (bi.z - bi.x) * (bi.w - bi.y);
  u64 m = 0;
  for (int j = 0; j < 64; ++j) {
    int gj = cb * 64 + j;
    float4 c = cbox[j];
    float iy1 = fmaxf(bi.x, c.x);
    float ix1 = fmaxf(bi.y, c.y);
    float iy2 = fminf(bi.z, c.z);
    float ix2 = fminf(bi.w, c.w);
    float inter = fmaxf(iy2 - iy1, 0.0f) * fmaxf(ix2 - ix1, 0.0f);
    float denom = bar + carea[j] - inter + 1e-9f;  // matches ref assoc order
    float iou = inter / denom;                      // IEEE fp32 div
    if ((gj > i) && (iou > 0.7f)) m |= (1ull << j);
  }
  mask[((size_t)b * PRE + i) * 64 + cb] = m;
}

// ---------------- greedy reduce: one wave per batch ----------------
__global__ __launch_bounds__(64) void k_reduce(const u64* __restrict__ mask,
                                               u32* __restrict__ outpos,
                                               u32* __restrict__ kc) {
  int b = blockIdx.x, t = threadIdx.x;
  const u64* m = mask + (size_t)b * PRE * 64 + t;  // row i word t at m[i*64]
  u64 remv = 0;  // thread t owns suppression bits for boxes [64t, 64t+64)
  const int CH = 16;
  const int NCH = PRE / CH;
  u64 bufA[CH], bufB[CH];
#pragma unroll
  for (int r = 0; r < CH; ++r) bufA[r] = m[(size_t)r * 64];
  for (int c = 0; c < NCH; ++c) {
#pragma unroll
    for (int r = 0; r < CH; ++r)
      bufB[r] = (c + 1 < NCH) ? m[(size_t)((c + 1) * CH + r) * 64] : 0ull;
#pragma unroll
    for (int r = 0; r < CH; ++r) {
      int i = c * CH + r;
      u64 rw = __shfl(remv, i >> 6);
      bool kept = ((rw >> (i & 63)) & 1ull) == 0ull;
      remv |= kept ? bufA[r] : 0ull;
    }
#pragma unroll
    for (int r = 0; r < CH; ++r) bufA[r] = bufB[r];
  }
  u64 keepw = ~remv;
  int nk = __popcll(keepw);
  int inc = nk;
#pragma unroll
  for (int off = 1; off < 64; off <<= 1) {
    int v = __shfl_up(inc, off);
    if (t >= off) inc += v;
  }
  int base = inc - nk;
  if (t == 63) kc[b] = (u32)inc;
  int r = base;
  for (int bit = 0; bit < 64; ++bit) {
    if ((keepw >> bit) & 1ull) {
      if (r < POST) outpos[(size_t)b * POST + r] = (u32)(t * 64 + bit);
      ++r;
    }
  }
}

// ---------------- final write: boxes (clipped) + scores, zero pad -----------
__global__ __launch_bounds__(256) void k_write(const float4* __restrict__ tb,
                                               const float* __restrict__ sscore,
                                               const u32* __restrict__ outpos,
                                               const u32* __restrict__ kc,
                                               float* __restrict__ out) {
  int b = blockIdx.y;
  int s = blockIdx.x * blockDim.x + threadIdx.x;
  if (s >= POST) return;
  u32 n = kc[b];
  if (n > POST) n = POST;
  float4 bx = make_float4(0.f, 0.f, 0.f, 0.f);
  float sc = 0.f;
  if ((u32)s < n) {
    u32 i = outpos[(size_t)b * POST + s];
    float4 v = tb[(size_t)b * PRE + i];
    bx.x = fminf(fmaxf(v.x, 0.f), 1.f);
    bx.y = fminf(fmaxf(v.y, 0.f), 1.f);
    bx.z = fminf(fmaxf(v.z, 0.f), 1.f);
    bx.w = fminf(fmaxf(v.w, 0.f), 1.f);
    sc = sscore[(size_t)b * PRE + i];
  }
  ((float4*)out)[(size_t)b * POST + s] = bx;
  out[(size_t)B_ * POST * 4 + (size_t)b * POST + s] = sc;
}

extern "C" void kernel_launch(void* const* d_in, const int* in_sizes, int n_in,
                              void* d_out, int out_size, void* d_ws,
                              size_t ws_size, hipStream_t stream) {
  const float* boxes = (const float*)d_in[0];   // [16,200000,4]
  const float* scores = (const float*)d_in[1];  // [16,200000,1]
  float* out = (float*)d_out;

  char* ws = (char*)d_ws;
  size_t off = 0;
  auto alloc = [&](size_t bytes) {
    size_t o = off;
    off = (off + bytes + 255) & ~(size_t)255;
    return o;
  };
  // zero-initialized region first (one memset)
  size_t o_hist1 = alloc((size_t)B_ * 4096 * 4);
  size_t o_hist2 = alloc((size_t)B_ * 4096 * 4);
  size_t o_hist3 = alloc((size_t)B_ * 256 * 4);
  size_t o_pref = alloc(B_ * 4);
  size_t o_K = alloc(B_ * 4);
  size_t o_cgt = alloc(B_ * 4);
  size_t o_ceq = alloc(B_ * 4);
  size_t zbytes = off;
  // non-zeroed scratch
  size_t o_sel = alloc((size_t)B_ * PRE * 8);
  size_t o_eq = alloc((size_t)B_ * PRE * 4);
  size_t o_sidx = alloc((size_t)B_ * PRE * 4);
  size_t o_sscore = alloc((size_t)B_ * PRE * 4);
  size_t o_tb = alloc((size_t)B_ * PRE * 16);
  size_t o_outpos = alloc((size_t)B_ * POST * 4);
  size_t o_kc = alloc(B_ * 4);
  size_t o_mask = alloc((size_t)B_ * PRE * 64 * 8);
  if (off > ws_size) return;  // workspace too small -> visible failure

  u32* hist1 = (u32*)(ws + o_hist1);
  u32* hist2 = (u32*)(ws + o_hist2);
  u32* hist3 = (u32*)(ws + o_hist3);
  u32* pref = (u32*)(ws + o_pref);
  u32* K = (u32*)(ws + o_K);
  u32* cgt = (u32*)(ws + o_cgt);
  u32* ceq = (u32*)(ws + o_ceq);
  u64* sel = (u64*)(ws + o_sel);
  u32* eqbuf = (u32*)(ws + o_eq);
  u32* sidx = (u32*)(ws + o_sidx);
  float* sscore = (float*)(ws + o_sscore);
  float4* tb = (float4*)(ws + o_tb);
  u32* outpos = (u32*)(ws + o_outpos);
  u32* kc = (u32*)(ws + o_kc);
  u64* mask = (u64*)(ws + o_mask);

  hipMemsetAsync(d_ws, 0, zbytes, stream);

  dim3 scanGrid(128, B_);
  k_hist1<<<scanGrid, 256, 0, stream>>>(scores, hist1);
  k_thresh<<<B_, 64, 0, stream>>>(hist1, 4096, 20, pref, K);
  k_hist2<<<scanGrid, 256, 0, stream>>>(scores, pref, hist2);
  k_thresh<<<B_, 64, 0, stream>>>(hist2, 4096, 8, pref, K);
  k_hist3<<<scanGrid, 256, 0, stream>>>(scores, pref, hist3);
  k_thresh<<<B_, 64, 0, stream>>>(hist3, 256, 0, pref, K);
  k_select<<<scanGrid, 256, 0, stream>>>(scores, pref, cgt, ceq, sel, eqbuf);
  k_tie<<<B_, 256, 0, stream>>>(pref, K, ceq, eqbuf, sel);
  k_sort<<<B_, 1024, 0, stream>>>(sel, sidx, sscore);
  k_gather<<<dim3(PRE / 256, B_), 256, 0, stream>>>((const float4*)boxes, sidx,
                                                    tb);
  k_mask<<<dim3(64, 64, B_), 64, 0, stream>>>(tb, mask);
  k_reduce<<<B_, 64, 0, stream>>>(mask, outpos, kc);
  k_write<<<dim3((POST + 255) / 256, B_), 256, 0, stream>>>(tb, sscore, outpos,
                                                            kc, out);
}

// Round 2
// 500.941 us; speedup vs baseline: 1.8419x; 1.8419x over previous
//
#include <hip/hip_runtime.h>
#include <stdint.h>

typedef unsigned int u32;
typedef unsigned long long u64;

#define B_ 16
#define N_ 200000
#define PRE 4096
#define POST 2000
#define CNT_PAD 64  // u32 stride between per-batch counters (256B: no false sharing)

// ---------------- histogram pass 1: bits [31:20] ----------------
__global__ __launch_bounds__(256) void k_hist1(const float* __restrict__ scores,
                                               u32* __restrict__ hist) {
  int b = blockIdx.y;
  __shared__ u32 h[4096];
  for (int i = threadIdx.x; i < 4096; i += blockDim.x) h[i] = 0;
  __syncthreads();
  const float* s = scores + (size_t)b * N_;
  for (int i = blockIdx.x * blockDim.x + threadIdx.x; i < N_;
       i += gridDim.x * blockDim.x) {
    u32 u = __float_as_uint(s[i]);
    atomicAdd(&h[u >> 20], 1u);
  }
  __syncthreads();
  u32* g = hist + (size_t)b * 4096;
  for (int i = threadIdx.x; i < 4096; i += blockDim.x) {
    u32 v = h[i];
    if (v) atomicAdd(&g[i], v);
  }
}

// ---------------- histogram pass 2: filter top12, bits [19:8] ----------------
__global__ __launch_bounds__(256) void k_hist2(const float* __restrict__ scores,
                                               const u32* __restrict__ pref,
                                               u32* __restrict__ hist) {
  int b = blockIdx.y;
  u32 P = pref[b];
  const float* s = scores + (size_t)b * N_;
  u32* g = hist + (size_t)b * 4096;
  for (int i = blockIdx.x * blockDim.x + threadIdx.x; i < N_;
       i += gridDim.x * blockDim.x) {
    u32 u = __float_as_uint(s[i]);
    if ((u & 0xFFF00000u) == P) atomicAdd(&g[(u >> 8) & 0xFFFu], 1u);
  }
}

// ---------------- histogram pass 3: filter top24, bits [7:0] ----------------
__global__ __launch_bounds__(256) void k_hist3(const float* __restrict__ scores,
                                               const u32* __restrict__ pref,
                                               u32* __restrict__ hist) {
  int b = blockIdx.y;
  u32 P = pref[b];
  const float* s = scores + (size_t)b * N_;
  u32* g = hist + (size_t)b * 256;
  for (int i = blockIdx.x * blockDim.x + threadIdx.x; i < N_;
       i += gridDim.x * blockDim.x) {
    u32 u = __float_as_uint(s[i]);
    if ((u & 0xFFFFFF00u) == P) atomicAdd(&g[u & 0xFFu], 1u);
  }
}

// ---------------- threshold finder (generic, 64 threads = 1 wave) -----------
__global__ __launch_bounds__(64) void k_thresh(const u32* __restrict__ hist,
                                               int nbins, int shift,
                                               u32* __restrict__ pref,
                                               u32* __restrict__ K) {
  int b = blockIdx.x;
  int t = threadIdx.x;
  const u32* h = hist + (size_t)b * nbins;
  int C = nbins >> 6;
  int base = t * C;
  u32 s = 0;
  for (int j = 0; j < C; ++j) s += h[base + j];
  u32 suf = s;  // inclusive suffix sum over lanes
#pragma unroll
  for (int off = 1; off < 64; off <<= 1) {
    u32 v = __shfl_down(suf, off);
    if (t + off < 64) suf += v;
  }
  u32 Kin = K[b];
  if (Kin == 0) Kin = PRE;  // memset-zeroed sentinel on first pass
  bool cond = (suf >= Kin) && (suf - s < Kin);
  if (cond) {
    u32 cum = suf - s;  // count strictly above my chunk
    for (int v = C - 1; v >= 0; --v) {
      u32 hv = h[base + v];
      cum += hv;
      if (cum >= Kin) {
        pref[b] |= ((u32)(base + v)) << shift;
        K[b] = Kin - (cum - hv);
        break;
      }
    }
  }
}

// ---------------- selection: >S* into sel, ==S* into eq buffer --------------
// Block-aggregated allocation: 1 atomicAdd per block per counter (padded),
// then a second pass writes at deterministic per-thread offsets.
__global__ __launch_bounds__(256) void k_select(const float* __restrict__ scores,
                                                const u32* __restrict__ pref,
                                                u32* __restrict__ cnt_gt,
                                                u32* __restrict__ cnt_eq,
                                                u64* __restrict__ sel,
                                                u32* __restrict__ eqbuf) {
  int b = blockIdx.y;
  u32 S = pref[b];
  const float* s = scores + (size_t)b * N_;
  int tid = threadIdx.x;
  int lane = tid & 63, wid = tid >> 6;
  int stride = gridDim.x * blockDim.x;
  int i0 = blockIdx.x * blockDim.x + tid;

  // pass 1: count
  u32 cg = 0, ce = 0;
  for (int i = i0; i < N_; i += stride) {
    u32 u = __float_as_uint(s[i]);
    cg += (u > S) ? 1u : 0u;
    ce += (u == S) ? 1u : 0u;
  }
  // wave inclusive scan
  u32 ig = cg, ie = ce;
#pragma unroll
  for (int off = 1; off < 64; off <<= 1) {
    u32 vg = __shfl_up(ig, off);
    u32 ve = __shfl_up(ie, off);
    if (lane >= off) {
      ig += vg;
      ie += ve;
    }
  }
  __shared__ u32 wg[4], we[4], baseg, basee;
  if (lane == 63) {
    wg[wid] = ig;
    we[wid] = ie;
  }
  __syncthreads();
  if (tid == 0) {
    u32 tg = wg[0] + wg[1] + wg[2] + wg[3];
    u32 te = we[0] + we[1] + we[2] + we[3];
    baseg = tg ? atomicAdd(&cnt_gt[(size_t)b * CNT_PAD], tg) : 0u;
    basee = te ? atomicAdd(&cnt_eq[(size_t)b * CNT_PAD], te) : 0u;
  }
  __syncthreads();
  u32 woffg = 0, woffe = 0;
  for (int w = 0; w < wid; ++w) {
    woffg += wg[w];
    woffe += we[w];
  }
  u32 pg = baseg + woffg + (ig - cg);  // my exclusive start
  u32 pe = basee + woffe + (ie - ce);

  // pass 2: write (elements are L2-hot)
  for (int i = i0; i < N_; i += stride) {
    u32 u = __float_as_uint(s[i]);
    if (u > S) {
      if (pg < PRE) sel[(size_t)b * PRE + pg] = ((u64)u << 32) | (u32)(~(u32)i);
      ++pg;
    } else if (u == S) {
      if (pe < PRE) eqbuf[(size_t)b * PRE + pe] = (u32)i;
      ++pe;
    }
  }
}

// ---------------- tie resolve: smallest Kf indices among equals -------------
__global__ __launch_bounds__(256) void k_tie(const u32* __restrict__ pref,
                                             const u32* __restrict__ K,
                                             const u32* __restrict__ cnt_eq,
                                             const u32* __restrict__ eqbuf,
                                             u64* __restrict__ sel) {
  int b = blockIdx.x;
  u32 Kf = K[b];
  u32 ne = cnt_eq[(size_t)b * CNT_PAD];
  if (ne > PRE) ne = PRE;
  u32 S = pref[b];
  u32 basep = PRE - Kf;
  const u32* eq = eqbuf + (size_t)b * PRE;
  for (u32 p = threadIdx.x; p < ne; p += blockDim.x) {
    u32 my = eq[p];
    u32 rank = 0;
    for (u32 q = 0; q < ne; ++q) rank += (eq[q] < my) ? 1u : 0u;
    if (rank < Kf)
      sel[(size_t)b * PRE + basep + rank] = ((u64)S << 32) | (u32)(~my);
  }
}

// ---------------- bitonic sort of 4096 keys (descending), per batch ---------
__global__ __launch_bounds__(1024) void k_sort(const u64* __restrict__ sel,
                                               u32* __restrict__ sidx,
                                               float* __restrict__ sscore) {
  __shared__ u64 k[PRE];
  int b = blockIdx.x, t = threadIdx.x;
  for (int i = t; i < PRE; i += 1024) k[i] = sel[(size_t)b * PRE + i];
  __syncthreads();
  for (int kk = 2; kk <= PRE; kk <<= 1) {
    for (int j = kk >> 1; j > 0; j >>= 1) {
      for (int i = t; i < PRE; i += 1024) {
        int ixj = i ^ j;
        if (ixj > i) {
          u64 a = k[i], bv = k[ixj];
          bool up = (i & kk) == 0;
          if (up ? (a < bv) : (a > bv)) {
            k[i] = bv;
            k[ixj] = a;
          }
        }
      }
      __syncthreads();
    }
  }
  for (int i = t; i < PRE; i += 1024) {
    u64 key = k[i];
    sidx[(size_t)b * PRE + i] = ~(u32)key;
    sscore[(size_t)b * PRE + i] = __uint_as_float((u32)(key >> 32));
  }
}

// ---------------- gather topk boxes ----------------
__global__ __launch_bounds__(256) void k_gather(const float4* __restrict__ boxes,
                                                const u32* __restrict__ sidx,
                                                float4* __restrict__ tb) {
  int b = blockIdx.y;
  int i = blockIdx.x * blockDim.x + threadIdx.x;
  if (i >= PRE) return;
  u32 idx = sidx[(size_t)b * PRE + i];
  tb[(size_t)b * PRE + i] = boxes[(size_t)b * N_ + idx];
}

// ---------------- NMS pairwise mask (64x64 tiles) ----------------
__global__ __launch_bounds__(64) void k_mask(const float4* __restrict__ tb,
                                             u64* __restrict__ mask) {
  int cb = blockIdx.x, rb = blockIdx.y, b = blockIdx.z;
  int t = threadIdx.x;
  int i = rb * 64 + t;
  if (cb < rb) {  // all column indices < row indices: no suppression bits
    mask[((size_t)b * PRE + i) * 64 + cb] = 0ull;
    return;
  }
  __shared__ float4 cbox[64];
  __shared__ float carea[64];
  float4 cj = tb[(size_t)b * PRE + cb * 64 + t];
  cbox[t] = cj;
  carea[t] = (cj.z - cj.x) * (cj.w - cj.y);  // (y2-y1)*(x2-x1)
  __syncthreads();
  float4 bi = tb[(size_t)b * PRE + i];
  float bar = (bi.z - bi.x) * (bi.w - bi.y);
  u64 m = 0;
  for (int j = 0; j < 64; ++j) {
    int gj = cb * 64 + j;
    float4 c = cbox[j];
    float iy1 = fmaxf(bi.x, c.x);
    float ix1 = fmaxf(bi.y, c.y);
    float iy2 = fminf(bi.z, c.z);
    float ix2 = fminf(bi.w, c.w);
    float inter = fmaxf(iy2 - iy1, 0.0f) * fmaxf(ix2 - ix1, 0.0f);
    float denom = bar + carea[j] - inter + 1e-9f;  // matches ref assoc order
    float iou = inter / denom;                      // IEEE fp32 div
    if ((gj > i) && (iou > 0.7f)) m |= (1ull << j);
  }
  mask[((size_t)b * PRE + i) * 64 + cb] = m;
}

// ---------------- greedy reduce: one wave per batch ----------------
__global__ __launch_bounds__(64) void k_reduce(const u64* __restrict__ mask,
                                               u32* __restrict__ outpos,
                                               u32* __restrict__ kc) {
  int b = blockIdx.x, t = threadIdx.x;
  const u64* m = mask + (size_t)b * PRE * 64 + t;  // row i word t at m[i*64]
  u64 remv = 0;  // thread t owns suppression bits for boxes [64t, 64t+64)
  const int CH = 16;
  const int NCH = PRE / CH;
  u64 bufA[CH], bufB[CH];
#pragma unroll
  for (int r = 0; r < CH; ++r) bufA[r] = m[(size_t)r * 64];
  for (int c = 0; c < NCH; ++c) {
#pragma unroll
    for (int r = 0; r < CH; ++r)
      bufB[r] = (c + 1 < NCH) ? m[(size_t)((c + 1) * CH + r) * 64] : 0ull;
#pragma unroll
    for (int r = 0; r < CH; ++r) {
      int i = c * CH + r;
      u64 rw = __shfl(remv, i >> 6);
      bool kept = ((rw >> (i & 63)) & 1ull) == 0ull;
      remv |= kept ? bufA[r] : 0ull;
    }
#pragma unroll
    for (int r = 0; r < CH; ++r) bufA[r] = bufB[r];
  }
  u64 keepw = ~remv;
  int nk = __popcll(keepw);
  int inc = nk;
#pragma unroll
  for (int off = 1; off < 64; off <<= 1) {
    int v = __shfl_up(inc, off);
    if (t >= off) inc += v;
  }
  int base = inc - nk;
  if (t == 63) kc[b] = (u32)inc;
  int r = base;
  for (int bit = 0; bit < 64; ++bit) {
    if ((keepw >> bit) & 1ull) {
      if (r < POST) outpos[(size_t)b * POST + r] = (u32)(t * 64 + bit);
      ++r;
    }
  }
}

// ---------------- final write: boxes (clipped) + scores, zero pad -----------
__global__ __launch_bounds__(256) void k_write(const float4* __restrict__ tb,
                                               const float* __restrict__ sscore,
                                               const u32* __restrict__ outpos,
                                               const u32* __restrict__ kc,
                                               float* __restrict__ out) {
  int b = blockIdx.y;
  int s = blockIdx.x * blockDim.x + threadIdx.x;
  if (s >= POST) return;
  u32 n = kc[b];
  if (n > POST) n = POST;
  float4 bx = make_float4(0.f, 0.f, 0.f, 0.f);
  float sc = 0.f;
  if ((u32)s < n) {
    u32 i = outpos[(size_t)b * POST + s];
    float4 v = tb[(size_t)b * PRE + i];
    bx.x = fminf(fmaxf(v.x, 0.f), 1.f);
    bx.y = fminf(fmaxf(v.y, 0.f), 1.f);
    bx.z = fminf(fmaxf(v.z, 0.f), 1.f);
    bx.w = fminf(fmaxf(v.w, 0.f), 1.f);
    sc = sscore[(size_t)b * PRE + i];
  }
  ((float4*)out)[(size_t)b * POST + s] = bx;
  out[(size_t)B_ * POST * 4 + (size_t)b * POST + s] = sc;
}

extern "C" void kernel_launch(void* const* d_in, const int* in_sizes, int n_in,
                              void* d_out, int out_size, void* d_ws,
                              size_t ws_size, hipStream_t stream) {
  const float* boxes = (const float*)d_in[0];   // [16,200000,4]
  const float* scores = (const float*)d_in[1];  // [16,200000,1]
  float* out = (float*)d_out;

  char* ws = (char*)d_ws;
  size_t off = 0;
  auto alloc = [&](size_t bytes) {
    size_t o = off;
    off = (off + bytes + 255) & ~(size_t)255;
    return o;
  };
  // zero-initialized region first (one memset)
  size_t o_hist1 = alloc((size_t)B_ * 4096 * 4);
  size_t o_hist2 = alloc((size_t)B_ * 4096 * 4);
  size_t o_hist3 = alloc((size_t)B_ * 256 * 4);
  size_t o_pref = alloc(B_ * 4);
  size_t o_K = alloc(B_ * 4);
  size_t o_cgt = alloc((size_t)B_ * CNT_PAD * 4);
  size_t o_ceq = alloc((size_t)B_ * CNT_PAD * 4);
  size_t zbytes = off;
  // non-zeroed scratch
  size_t o_sel = alloc((size_t)B_ * PRE * 8);
  size_t o_eq = alloc((size_t)B_ * PRE * 4);
  size_t o_sidx = alloc((size_t)B_ * PRE * 4);
  size_t o_sscore = alloc((size_t)B_ * PRE * 4);
  size_t o_tb = alloc((size_t)B_ * PRE * 16);
  size_t o_outpos = alloc((size_t)B_ * POST * 4);
  size_t o_kc = alloc(B_ * 4);
  size_t o_mask = alloc((size_t)B_ * PRE * 64 * 8);
  if (off > ws_size) return;  // workspace too small -> visible failure

  u32* hist1 = (u32*)(ws + o_hist1);
  u32* hist2 = (u32*)(ws + o_hist2);
  u32* hist3 = (u32*)(ws + o_hist3);
  u32* pref = (u32*)(ws + o_pref);
  u32* K = (u32*)(ws + o_K);
  u32* cgt = (u32*)(ws + o_cgt);
  u32* ceq = (u32*)(ws + o_ceq);
  u64* sel = (u64*)(ws + o_sel);
  u32* eqbuf = (u32*)(ws + o_eq);
  u32* sidx = (u32*)(ws + o_sidx);
  float* sscore = (float*)(ws + o_sscore);
  float4* tb = (float4*)(ws + o_tb);
  u32* outpos = (u32*)(ws + o_outpos);
  u32* kc = (u32*)(ws + o_kc);
  u64* mask = (u64*)(ws + o_mask);

  hipMemsetAsync(d_ws, 0, zbytes, stream);

  dim3 scanGrid(128, B_);
  k_hist1<<<scanGrid, 256, 0, stream>>>(scores, hist1);
  k_thresh<<<B_, 64, 0, stream>>>(hist1, 4096, 20, pref, K);
  k_hist2<<<scanGrid, 256, 0, stream>>>(scores, pref, hist2);
  k_thresh<<<B_, 64, 0, stream>>>(hist2, 4096, 8, pref, K);
  k_hist3<<<scanGrid, 256, 0, stream>>>(scores, pref, hist3);
  k_thresh<<<B_, 64, 0, stream>>>(hist3, 256, 0, pref, K);
  k_select<<<scanGrid, 256, 0, stream>>>(scores, pref, cgt, ceq, sel, eqbuf);
  k_tie<<<B_, 256, 0, stream>>>(pref, K, ceq, eqbuf, sel);
  k_sort<<<B_, 1024, 0, stream>>>(sel, sidx, sscore);
  k_gather<<<dim3(PRE / 256, B_), 256, 0, stream>>>((const float4*)boxes, sidx,
                                                    tb);
  k_mask<<<dim3(64, 64, B_), 64, 0, stream>>>(tb, mask);
  k_reduce<<<B_, 64, 0, stream>>>(mask, outpos, kc);
  k_write<<<dim3((POST + 255) / 256, B_), 256, 0, stream>>>(tb, sscore, outpos,
                                                            kc, out);
}

// Round 3
// 345.759 us; speedup vs baseline: 2.6686x; 1.4488x over previous
//
#include <hip/hip_runtime.h>
#include <stdint.h>
#include <math.h>

typedef unsigned int u32;
typedef unsigned long long u64;

#define B_ 16
#define N_ 200000
#define PRE 4096
#define POST 2000
#define CNT_PAD 64  // u32 stride between per-batch counters (256B apart)

// ---------------- histogram pass 1: bits [31:20] ----------------
__global__ __launch_bounds__(256) void k_hist1(const float* __restrict__ scores,
                                               u32* __restrict__ hist) {
  int b = blockIdx.y;
  __shared__ u32 h[4096];
  for (int i = threadIdx.x; i < 4096; i += blockDim.x) h[i] = 0;
  __syncthreads();
  const float* s = scores + (size_t)b * N_;
  for (int i = blockIdx.x * blockDim.x + threadIdx.x; i < N_;
       i += gridDim.x * blockDim.x) {
    u32 u = __float_as_uint(s[i]);
    atomicAdd(&h[u >> 20], 1u);
  }
  __syncthreads();
  u32* g = hist + (size_t)b * 4096;
  for (int i = threadIdx.x; i < 4096; i += blockDim.x) {
    u32 v = h[i];
    if (v) atomicAdd(&g[i], v);
  }
}

// ---------------- histogram pass 2: filter top12, bits [19:8] ----------------
__global__ __launch_bounds__(256) void k_hist2(const float* __restrict__ scores,
                                               const u32* __restrict__ pref,
                                               u32* __restrict__ hist) {
  int b = blockIdx.y;
  u32 P = pref[b];
  const float* s = scores + (size_t)b * N_;
  u32* g = hist + (size_t)b * 4096;
  for (int i = blockIdx.x * blockDim.x + threadIdx.x; i < N_;
       i += gridDim.x * blockDim.x) {
    u32 u = __float_as_uint(s[i]);
    if ((u & 0xFFF00000u) == P) atomicAdd(&g[(u >> 8) & 0xFFFu], 1u);
  }
}

// ---------------- histogram pass 3: filter top24, bits [7:0] ----------------
__global__ __launch_bounds__(256) void k_hist3(const float* __restrict__ scores,
                                               const u32* __restrict__ pref,
                                               u32* __restrict__ hist) {
  int b = blockIdx.y;
  u32 P = pref[b];
  const float* s = scores + (size_t)b * N_;
  u32* g = hist + (size_t)b * 256;
  for (int i = blockIdx.x * blockDim.x + threadIdx.x; i < N_;
       i += gridDim.x * blockDim.x) {
    u32 u = __float_as_uint(s[i]);
    if ((u & 0xFFFFFF00u) == P) atomicAdd(&g[u & 0xFFu], 1u);
  }
}

// ---------------- threshold finder (generic, 64 threads = 1 wave) -----------
__global__ __launch_bounds__(64) void k_thresh(const u32* __restrict__ hist,
                                               int nbins, int shift,
                                               u32* __restrict__ pref,
                                               u32* __restrict__ K) {
  int b = blockIdx.x;
  int t = threadIdx.x;
  const u32* h = hist + (size_t)b * nbins;
  int C = nbins >> 6;
  int base = t * C;
  u32 s = 0;
  for (int j = 0; j < C; ++j) s += h[base + j];
  u32 suf = s;  // inclusive suffix sum over lanes
#pragma unroll
  for (int off = 1; off < 64; off <<= 1) {
    u32 v = __shfl_down(suf, off);
    if (t + off < 64) suf += v;
  }
  u32 Kin = K[b];
  if (Kin == 0) Kin = PRE;  // memset-zeroed sentinel on first pass
  bool cond = (suf >= Kin) && (suf - s < Kin);
  if (cond) {
    u32 cum = suf - s;  // count strictly above my chunk
    for (int v = C - 1; v >= 0; --v) {
      u32 hv = h[base + v];
      cum += hv;
      if (cum >= Kin) {
        pref[b] |= ((u32)(base + v)) << shift;
        K[b] = Kin - (cum - hv);
        break;
      }
    }
  }
}

// ---------------- selection: >S* into sel, ==S* into eq buffer --------------
__global__ __launch_bounds__(256) void k_select(const float* __restrict__ scores,
                                                const u32* __restrict__ pref,
                                                u32* __restrict__ cnt_gt,
                                                u32* __restrict__ cnt_eq,
                                                u64* __restrict__ sel,
                                                u32* __restrict__ eqbuf) {
  int b = blockIdx.y;
  u32 S = pref[b];
  const float* s = scores + (size_t)b * N_;
  int tid = threadIdx.x;
  int lane = tid & 63, wid = tid >> 6;
  int stride = gridDim.x * blockDim.x;
  int i0 = blockIdx.x * blockDim.x + tid;

  u32 cg = 0, ce = 0;
  for (int i = i0; i < N_; i += stride) {
    u32 u = __float_as_uint(s[i]);
    cg += (u > S) ? 1u : 0u;
    ce += (u == S) ? 1u : 0u;
  }
  u32 ig = cg, ie = ce;
#pragma unroll
  for (int off = 1; off < 64; off <<= 1) {
    u32 vg = __shfl_up(ig, off);
    u32 ve = __shfl_up(ie, off);
    if (lane >= off) {
      ig += vg;
      ie += ve;
    }
  }
  __shared__ u32 wg[4], we[4], baseg, basee;
  if (lane == 63) {
    wg[wid] = ig;
    we[wid] = ie;
  }
  __syncthreads();
  if (tid == 0) {
    u32 tg = wg[0] + wg[1] + wg[2] + wg[3];
    u32 te = we[0] + we[1] + we[2] + we[3];
    baseg = tg ? atomicAdd(&cnt_gt[(size_t)b * CNT_PAD], tg) : 0u;
    basee = te ? atomicAdd(&cnt_eq[(size_t)b * CNT_PAD], te) : 0u;
  }
  __syncthreads();
  u32 woffg = 0, woffe = 0;
  for (int w = 0; w < wid; ++w) {
    woffg += wg[w];
    woffe += we[w];
  }
  u32 pg = baseg + woffg + (ig - cg);
  u32 pe = basee + woffe + (ie - ce);

  for (int i = i0; i < N_; i += stride) {
    u32 u = __float_as_uint(s[i]);
    if (u > S) {
      if (pg < PRE) sel[(size_t)b * PRE + pg] = ((u64)u << 32) | (u32)(~(u32)i);
      ++pg;
    } else if (u == S) {
      if (pe < PRE) eqbuf[(size_t)b * PRE + pe] = (u32)i;
      ++pe;
    }
  }
}

// ---------------- sort (+ tie resolve + box gather fused) -------------------
__global__ __launch_bounds__(1024) void k_sort(const u64* __restrict__ sel,
                                               const u32* __restrict__ eqbuf,
                                               const u32* __restrict__ pref,
                                               const u32* __restrict__ K,
                                               const u32* __restrict__ cnt_eq,
                                               const float4* __restrict__ boxes,
                                               float4* __restrict__ tb,
                                               float* __restrict__ sscore) {
  __shared__ u64 k[PRE];
  int b = blockIdx.x, t = threadIdx.x;
  for (int i = t; i < PRE; i += 1024) k[i] = sel[(size_t)b * PRE + i];
  __syncthreads();
  // tie fill: smallest-index Kf equals go at slots [PRE-Kf, PRE)
  {
    u32 Kf = K[b];
    u32 S = pref[b];
    u32 ne = cnt_eq[(size_t)b * CNT_PAD];
    if (ne > PRE) ne = PRE;
    u32 basep = PRE - Kf;
    const u32* eq = eqbuf + (size_t)b * PRE;
    for (u32 p = t; p < ne; p += 1024) {
      u32 my = eq[p];
      u32 rank = 0;
      for (u32 q = 0; q < ne; ++q) rank += (eq[q] < my) ? 1u : 0u;
      if (rank < Kf) k[basep + rank] = ((u64)S << 32) | (u32)(~my);
    }
  }
  __syncthreads();
  for (int kk = 2; kk <= PRE; kk <<= 1) {
    for (int j = kk >> 1; j > 0; j >>= 1) {
      for (int i = t; i < PRE; i += 1024) {
        int ixj = i ^ j;
        if (ixj > i) {
          u64 a = k[i], bv = k[ixj];
          bool up = (i & kk) == 0;
          if (up ? (a < bv) : (a > bv)) {
            k[i] = bv;
            k[ixj] = a;
          }
        }
      }
      __syncthreads();
    }
  }
  for (int i = t; i < PRE; i += 1024) {
    u64 key = k[i];
    u32 idx = ~(u32)key;
    sscore[(size_t)b * PRE + i] = __uint_as_float((u32)(key >> 32));
    tb[(size_t)b * PRE + i] = boxes[(size_t)b * N_ + idx];
  }
}

// ---------------- NMS pairwise mask: upper-triangle 64x64 tiles only --------
__global__ __launch_bounds__(64) void k_mask(const float4* __restrict__ tb,
                                             u64* __restrict__ mask) {
  int b = blockIdx.y;
  int tri = blockIdx.x;  // 0..2079 -> (rb, cb) with rb <= cb < 64
  double disc = 16641.0 - 8.0 * (double)tri;  // 129^2 - 8*tri
  int rb = (int)((129.0 - sqrt(disc)) * 0.5);
#define OFFS(r) ((r)*64 - ((r) * ((r)-1)) / 2)
  while (rb > 0 && OFFS(rb) > tri) --rb;
  while (rb < 63 && OFFS(rb + 1) <= tri) ++rb;
  int cb = rb + (tri - OFFS(rb));
#undef OFFS
  int t = threadIdx.x;
  __shared__ float4 cbox[64];
  __shared__ float carea[64];
  float4 cj = tb[(size_t)b * PRE + cb * 64 + t];
  cbox[t] = cj;
  carea[t] = (cj.z - cj.x) * (cj.w - cj.y);
  __syncthreads();
  int i = rb * 64 + t;
  float4 bi = tb[(size_t)b * PRE + i];
  float bar = (bi.z - bi.x) * (bi.w - bi.y);
  // exact equivalence to rnd32(inter/denom) > 0.7f (denom>0):
  //   suppress <=> (double)inter >= MD * (double)denom
  const double MD = (double)0.7f + 0x1.0p-25;  // midpoint; tie rounds up (even)
  u64 validm = (cb > rb) ? ~0ull : ((t == 63) ? 0ull : (~0ull << (t + 1)));
  u64 m = 0;
#pragma unroll 8
  for (int j = 0; j < 64; ++j) {
    float4 c = cbox[j];
    float iy1 = fmaxf(bi.x, c.x);
    float ix1 = fmaxf(bi.y, c.y);
    float iy2 = fminf(bi.z, c.z);
    float ix2 = fminf(bi.w, c.w);
    float inter = fmaxf(iy2 - iy1, 0.0f) * fmaxf(ix2 - ix1, 0.0f);
    float denom = bar + carea[j] - inter + 1e-9f;  // ((bar+ca)-inter)+1e-9
    double di = (double)inter, dd = (double)denom;
    bool sup = (dd > 0.0) ? (di >= MD * dd) : (dd == 0.0 ? (di > 0.0) : false);
    if (sup) m |= (1ull << j);
  }
  m &= validm;
  mask[((size_t)b * PRE + i) * 64 + cb] = m;
}

// ---------------- greedy reduce + output write: one wave per batch ----------
__global__ __launch_bounds__(64, 1) void k_reduce(const u64* __restrict__ mask,
                                                  const float4* __restrict__ tb,
                                                  const float* __restrict__ sscore,
                                                  float* __restrict__ out) {
  int b = blockIdx.x, t = threadIdx.x;
  const u64* m = mask + ((size_t)b * PRE) * 64 + t;
  u64 remv = 0;   // suppression bits for columns [64t, 64t+64)
  u64 keepm = 0;  // keep bits for rows [64t, 64t+64) (valid once processed)
  int cnt = 0;    // kept rows so far (uniform)
  u64 bufA[64], bufB[64];

#define LOADBLK(buf, rb_)                                                   \
  do {                                                                      \
    if ((rb_) < 64 && t >= (rb_)) {                                         \
      _Pragma("unroll") for (int r_ = 0; r_ < 64; ++r_) buf[r_] =           \
          m[(size_t)((rb_)*64 + r_) * 64];                                  \
    } else {                                                                \
      _Pragma("unroll") for (int r_ = 0; r_ < 64; ++r_) buf[r_] = 0ull;     \
    }                                                                       \
  } while (0)

#define PROCBLK(buf, rb_)                                                   \
  do {                                                                      \
    u64 rm = remv, kb = 0;                                                  \
    _Pragma("unroll") for (int r_ = 0; r_ < 64; ++r_) {                     \
      u64 bit = 1ull << r_;                                                 \
      bool kept = (rm & bit) == 0ull;                                       \
      if (kept) {                                                           \
        kb |= bit;                                                          \
        rm |= buf[r_];                                                      \
      }                                                                     \
    }                                                                       \
    kb = (u64)__shfl((long long)kb, (rb_));                                 \
    _Pragma("unroll") for (int r_ = 0; r_ < 64; ++r_) {                     \
      if ((kb >> r_) & 1ull) remv |= buf[r_];                               \
    }                                                                       \
    if (t == (rb_)) keepm = kb;                                             \
    cnt += __popcll(kb);                                                    \
  } while (0)

  LOADBLK(bufA, 0);
  int done = 0;
  for (int rb = 0; rb < 64 && !done; rb += 2) {
    LOADBLK(bufB, rb + 1);
    PROCBLK(bufA, rb);
    if (cnt >= POST) done = 1;
    if (!done) {
      LOADBLK(bufA, rb + 2);
      PROCBLK(bufB, rb + 1);
      if (cnt >= POST) done = 1;
    }
  }
#undef LOADBLK
#undef PROCBLK

  // rank among kept, then write output directly
  int nk = __popcll(keepm);
  int inc = nk;
#pragma unroll
  for (int off = 1; off < 64; off <<= 1) {
    int v = __shfl_up(inc, off);
    if (t >= off) inc += v;
  }
  int base = inc - nk;

  const float4* tbb = tb + (size_t)b * PRE;
  const float* ssb = sscore + (size_t)b * PRE;
  float4* outb = (float4*)out + (size_t)b * POST;
  float* outs = out + (size_t)B_ * POST * 4 + (size_t)b * POST;

  int r = base;
  for (int bit = 0; bit < 64; ++bit) {
    if ((keepm >> bit) & 1ull) {
      if (r < POST) {
        int i = t * 64 + bit;
        float4 v = tbb[i];
        float4 bx;
        bx.x = fminf(fmaxf(v.x, 0.f), 1.f);
        bx.y = fminf(fmaxf(v.y, 0.f), 1.f);
        bx.z = fminf(fmaxf(v.z, 0.f), 1.f);
        bx.w = fminf(fmaxf(v.w, 0.f), 1.f);
        outb[r] = bx;
        outs[r] = ssb[i];
      }
      ++r;
    }
  }
  int ntot = cnt < POST ? cnt : POST;
  for (int s = ntot + t; s < POST; s += 64) {
    outb[s] = make_float4(0.f, 0.f, 0.f, 0.f);
    outs[s] = 0.f;
  }
}

extern "C" void kernel_launch(void* const* d_in, const int* in_sizes, int n_in,
                              void* d_out, int out_size, void* d_ws,
                              size_t ws_size, hipStream_t stream) {
  const float* boxes = (const float*)d_in[0];   // [16,200000,4]
  const float* scores = (const float*)d_in[1];  // [16,200000,1]
  float* out = (float*)d_out;

  char* ws = (char*)d_ws;
  size_t off = 0;
  auto alloc = [&](size_t bytes) {
    size_t o = off;
    off = (off + bytes + 255) & ~(size_t)255;
    return o;
  };
  // zero-initialized region first (one memset)
  size_t o_hist1 = alloc((size_t)B_ * 4096 * 4);
  size_t o_hist2 = alloc((size_t)B_ * 4096 * 4);
  size_t o_hist3 = alloc((size_t)B_ * 256 * 4);
  size_t o_pref = alloc(B_ * 4);
  size_t o_K = alloc(B_ * 4);
  size_t o_cgt = alloc((size_t)B_ * CNT_PAD * 4);
  size_t o_ceq = alloc((size_t)B_ * CNT_PAD * 4);
  size_t zbytes = off;
  // non-zeroed scratch
  size_t o_sel = alloc((size_t)B_ * PRE * 8);
  size_t o_eq = alloc((size_t)B_ * PRE * 4);
  size_t o_sscore = alloc((size_t)B_ * PRE * 4);
  size_t o_tb = alloc((size_t)B_ * PRE * 16);
  size_t o_mask = alloc((size_t)B_ * PRE * 64 * 8);
  if (off > ws_size) return;  // workspace too small -> visible failure

  u32* hist1 = (u32*)(ws + o_hist1);
  u32* hist2 = (u32*)(ws + o_hist2);
  u32* hist3 = (u32*)(ws + o_hist3);
  u32* pref = (u32*)(ws + o_pref);
  u32* K = (u32*)(ws + o_K);
  u32* cgt = (u32*)(ws + o_cgt);
  u32* ceq = (u32*)(ws + o_ceq);
  u64* sel = (u64*)(ws + o_sel);
  u32* eqbuf = (u32*)(ws + o_eq);
  float* sscore = (float*)(ws + o_sscore);
  float4* tb = (float4*)(ws + o_tb);
  u64* mask = (u64*)(ws + o_mask);

  hipMemsetAsync(d_ws, 0, zbytes, stream);

  dim3 scanGrid(128, B_);
  k_hist1<<<scanGrid, 256, 0, stream>>>(scores, hist1);
  k_thresh<<<B_, 64, 0, stream>>>(hist1, 4096, 20, pref, K);
  k_hist2<<<scanGrid, 256, 0, stream>>>(scores, pref, hist2);
  k_thresh<<<B_, 64, 0, stream>>>(hist2, 4096, 8, pref, K);
  k_hist3<<<scanGrid, 256, 0, stream>>>(scores, pref, hist3);
  k_thresh<<<B_, 64, 0, stream>>>(hist3, 256, 0, pref, K);
  k_select<<<scanGrid, 256, 0, stream>>>(scores, pref, cgt, ceq, sel, eqbuf);
  k_sort<<<B_, 1024, 0, stream>>>(sel, eqbuf, pref, K, ceq,
                                  (const float4*)boxes, tb, sscore);
  k_mask<<<dim3(2080, B_), 64, 0, stream>>>(tb, mask);
  k_reduce<<<B_, 64, 0, stream>>>(mask, tb, sscore, out);
}

// Round 4
// 334.246 us; speedup vs baseline: 2.7605x; 1.0344x over previous
//
#include <hip/hip_runtime.h>
#include <stdint.h>
#include <math.h>

typedef unsigned int u32;
typedef unsigned long long u64;

#define B_ 16
#define N_ 200000
#define PRE 4096
#define POST 2000
#define CNT_PAD 64  // u32 stride between per-batch counters (256B apart)

// ---------------- histogram pass 1: bits [31:20] ----------------
__global__ __launch_bounds__(256) void k_hist1(const float* __restrict__ scores,
                                               u32* __restrict__ hist) {
  int b = blockIdx.y;
  __shared__ u32 h[4096];
  for (int i = threadIdx.x; i < 4096; i += blockDim.x) h[i] = 0;
  __syncthreads();
  const float* s = scores + (size_t)b * N_;
  for (int i = blockIdx.x * blockDim.x + threadIdx.x; i < N_;
       i += gridDim.x * blockDim.x) {
    u32 u = __float_as_uint(s[i]);
    atomicAdd(&h[u >> 20], 1u);
  }
  __syncthreads();
  u32* g = hist + (size_t)b * 4096;
  for (int i = threadIdx.x; i < 4096; i += blockDim.x) {
    u32 v = h[i];
    if (v) atomicAdd(&g[i], v);
  }
}

// ---------------- histogram pass 2: filter top12, bits [19:8] ----------------
__global__ __launch_bounds__(256) void k_hist2(const float* __restrict__ scores,
                                               const u32* __restrict__ pref,
                                               u32* __restrict__ hist) {
  int b = blockIdx.y;
  u32 P = pref[b];
  const float* s = scores + (size_t)b * N_;
  u32* g = hist + (size_t)b * 4096;
  for (int i = blockIdx.x * blockDim.x + threadIdx.x; i < N_;
       i += gridDim.x * blockDim.x) {
    u32 u = __float_as_uint(s[i]);
    if ((u & 0xFFF00000u) == P) atomicAdd(&g[(u >> 8) & 0xFFFu], 1u);
  }
}

// ---------------- histogram pass 3: filter top24, bits [7:0] ----------------
__global__ __launch_bounds__(256) void k_hist3(const float* __restrict__ scores,
                                               const u32* __restrict__ pref,
                                               u32* __restrict__ hist) {
  int b = blockIdx.y;
  u32 P = pref[b];
  const float* s = scores + (size_t)b * N_;
  u32* g = hist + (size_t)b * 256;
  for (int i = blockIdx.x * blockDim.x + threadIdx.x; i < N_;
       i += gridDim.x * blockDim.x) {
    u32 u = __float_as_uint(s[i]);
    if ((u & 0xFFFFFF00u) == P) atomicAdd(&g[u & 0xFFu], 1u);
  }
}

// ---------------- threshold finder (generic, 64 threads = 1 wave) -----------
__global__ __launch_bounds__(64) void k_thresh(const u32* __restrict__ hist,
                                               int nbins, int shift,
                                               u32* __restrict__ pref,
                                               u32* __restrict__ K) {
  int b = blockIdx.x;
  int t = threadIdx.x;
  const u32* h = hist + (size_t)b * nbins;
  int C = nbins >> 6;
  int base = t * C;
  u32 s = 0;
  for (int j = 0; j < C; ++j) s += h[base + j];
  u32 suf = s;  // inclusive suffix sum over lanes
#pragma unroll
  for (int off = 1; off < 64; off <<= 1) {
    u32 v = __shfl_down(suf, off);
    if (t + off < 64) suf += v;
  }
  u32 Kin = K[b];
  if (Kin == 0) Kin = PRE;  // memset-zeroed sentinel on first pass
  bool cond = (suf >= Kin) && (suf - s < Kin);
  if (cond) {
    u32 cum = suf - s;  // count strictly above my chunk
    for (int v = C - 1; v >= 0; --v) {
      u32 hv = h[base + v];
      cum += hv;
      if (cum >= Kin) {
        pref[b] |= ((u32)(base + v)) << shift;
        K[b] = Kin - (cum - hv);
        break;
      }
    }
  }
}

// ---------------- selection: >S* into sel, ==S* into eq buffer --------------
__global__ __launch_bounds__(256) void k_select(const float* __restrict__ scores,
                                                const u32* __restrict__ pref,
                                                u32* __restrict__ cnt_gt,
                                                u32* __restrict__ cnt_eq,
                                                u64* __restrict__ sel,
                                                u32* __restrict__ eqbuf) {
  int b = blockIdx.y;
  u32 S = pref[b];
  const float* s = scores + (size_t)b * N_;
  int tid = threadIdx.x;
  int lane = tid & 63, wid = tid >> 6;
  int stride = gridDim.x * blockDim.x;
  int i0 = blockIdx.x * blockDim.x + tid;

  u32 cg = 0, ce = 0;
  for (int i = i0; i < N_; i += stride) {
    u32 u = __float_as_uint(s[i]);
    cg += (u > S) ? 1u : 0u;
    ce += (u == S) ? 1u : 0u;
  }
  u32 ig = cg, ie = ce;
#pragma unroll
  for (int off = 1; off < 64; off <<= 1) {
    u32 vg = __shfl_up(ig, off);
    u32 ve = __shfl_up(ie, off);
    if (lane >= off) {
      ig += vg;
      ie += ve;
    }
  }
  __shared__ u32 wg[4], we[4], baseg, basee;
  if (lane == 63) {
    wg[wid] = ig;
    we[wid] = ie;
  }
  __syncthreads();
  if (tid == 0) {
    u32 tg = wg[0] + wg[1] + wg[2] + wg[3];
    u32 te = we[0] + we[1] + we[2] + we[3];
    baseg = tg ? atomicAdd(&cnt_gt[(size_t)b * CNT_PAD], tg) : 0u;
    basee = te ? atomicAdd(&cnt_eq[(size_t)b * CNT_PAD], te) : 0u;
  }
  __syncthreads();
  u32 woffg = 0, woffe = 0;
  for (int w = 0; w < wid; ++w) {
    woffg += wg[w];
    woffe += we[w];
  }
  u32 pg = baseg + woffg + (ig - cg);
  u32 pe = basee + woffe + (ie - ce);

  for (int i = i0; i < N_; i += stride) {
    u32 u = __float_as_uint(s[i]);
    if (u > S) {
      if (pg < PRE) sel[(size_t)b * PRE + pg] = ((u64)u << 32) | (u32)(~(u32)i);
      ++pg;
    } else if (u == S) {
      if (pe < PRE) eqbuf[(size_t)b * PRE + pe] = (u32)i;
      ++pe;
    }
  }
}

// ---------------- sort (+ tie resolve + box gather fused) -------------------
__global__ __launch_bounds__(1024) void k_sort(const u64* __restrict__ sel,
                                               const u32* __restrict__ eqbuf,
                                               const u32* __restrict__ pref,
                                               const u32* __restrict__ K,
                                               const u32* __restrict__ cnt_eq,
                                               const float4* __restrict__ boxes,
                                               float4* __restrict__ tb,
                                               float* __restrict__ sscore) {
  __shared__ u64 k[PRE];
  int b = blockIdx.x, t = threadIdx.x;
  for (int i = t; i < PRE; i += 1024) k[i] = sel[(size_t)b * PRE + i];
  __syncthreads();
  // tie fill: smallest-index Kf equals go at slots [PRE-Kf, PRE)
  {
    u32 Kf = K[b];
    u32 S = pref[b];
    u32 ne = cnt_eq[(size_t)b * CNT_PAD];
    if (ne > PRE) ne = PRE;
    u32 basep = PRE - Kf;
    const u32* eq = eqbuf + (size_t)b * PRE;
    for (u32 p = t; p < ne; p += 1024) {
      u32 my = eq[p];
      u32 rank = 0;
      for (u32 q = 0; q < ne; ++q) rank += (eq[q] < my) ? 1u : 0u;
      if (rank < Kf) k[basep + rank] = ((u64)S << 32) | (u32)(~my);
    }
  }
  __syncthreads();
  for (int kk = 2; kk <= PRE; kk <<= 1) {
    for (int j = kk >> 1; j > 0; j >>= 1) {
      for (int i = t; i < PRE; i += 1024) {
        int ixj = i ^ j;
        if (ixj > i) {
          u64 a = k[i], bv = k[ixj];
          bool up = (i & kk) == 0;
          if (up ? (a < bv) : (a > bv)) {
            k[i] = bv;
            k[ixj] = a;
          }
        }
      }
      __syncthreads();
    }
  }
  for (int i = t; i < PRE; i += 1024) {
    u64 key = k[i];
    u32 idx = ~(u32)key;
    sscore[(size_t)b * PRE + i] = __uint_as_float((u32)(key >> 32));
    tb[(size_t)b * PRE + i] = boxes[(size_t)b * N_ + idx];
  }
}

// ---------------- NMS pairwise mask: upper-triangle 64x64 tiles only --------
__global__ __launch_bounds__(64) void k_mask(const float4* __restrict__ tb,
                                             u64* __restrict__ mask) {
  int b = blockIdx.y;
  int tri = blockIdx.x;  // 0..2079 -> (rb, cb) with rb <= cb < 64
  double disc = 16641.0 - 8.0 * (double)tri;  // 129^2 - 8*tri
  int rb = (int)((129.0 - sqrt(disc)) * 0.5);
#define OFFS(r) ((r)*64 - ((r) * ((r)-1)) / 2)
  while (rb > 0 && OFFS(rb) > tri) --rb;
  while (rb < 63 && OFFS(rb + 1) <= tri) ++rb;
  int cb = rb + (tri - OFFS(rb));
#undef OFFS
  int t = threadIdx.x;
  __shared__ float4 cbox[64];
  __shared__ float carea[64];
  float4 cj = tb[(size_t)b * PRE + cb * 64 + t];
  cbox[t] = cj;
  carea[t] = (cj.z - cj.x) * (cj.w - cj.y);
  __syncthreads();
  int i = rb * 64 + t;
  float4 bi = tb[(size_t)b * PRE + i];
  float bar = (bi.z - bi.x) * (bi.w - bi.y);
  // exact equivalence to rnd32(inter/denom) > 0.7f (denom>0):
  //   suppress <=> (double)inter >= MD * (double)denom
  const double MD = (double)0.7f + 0x1.0p-25;  // midpoint; tie rounds up (even)
  u64 validm = (cb > rb) ? ~0ull : ((t == 63) ? 0ull : (~0ull << (t + 1)));
  u64 m = 0;
#pragma unroll 8
  for (int j = 0; j < 64; ++j) {
    float4 c = cbox[j];
    float iy1 = fmaxf(bi.x, c.x);
    float ix1 = fmaxf(bi.y, c.y);
    float iy2 = fminf(bi.z, c.z);
    float ix2 = fminf(bi.w, c.w);
    float inter = fmaxf(iy2 - iy1, 0.0f) * fmaxf(ix2 - ix1, 0.0f);
    float denom = bar + carea[j] - inter + 1e-9f;  // ((bar+ca)-inter)+1e-9
    double di = (double)inter, dd = (double)denom;
    bool sup = (dd > 0.0) ? (di >= MD * dd) : (dd == 0.0 ? (di > 0.0) : false);
    if (sup) m |= (1ull << j);
  }
  m &= validm;
  mask[((size_t)b * PRE + i) * 64 + cb] = m;
}

// ---------------- greedy reduce + output write: one wave per batch ----------
// Half-block (32-row) register double-buffer: 64+64=128 VGPR of buffers,
// stays under the 256-VGPR cliff (R3's 64-row version spilled to scratch).
__global__ __launch_bounds__(64, 1) void k_reduce(const u64* __restrict__ mask,
                                                  const float4* __restrict__ tb,
                                                  const float* __restrict__ sscore,
                                                  float* __restrict__ out) {
  int b = blockIdx.x, t = threadIdx.x;
  const u64* m = mask + ((size_t)b * PRE) * 64 + t;
  u64 remv = 0;   // suppression bits for columns [64t, 64t+64)
  u64 keepm = 0;  // keep bits for rows [64t, 64t+64)
  int cnt = 0;    // kept rows so far (uniform)
  u64 bufA[32], bufB[32];

  // idx = half-block index 0..127; rb = idx>>1, h = idx&1
#define LOADH(buf, idx_)                                                     \
  do {                                                                       \
    int rb_ = (idx_) >> 1;                                                   \
    if ((idx_) < 128 && t >= rb_) {                                          \
      int row0_ = rb_ * 64 + ((idx_)&1) * 32;                                \
      _Pragma("unroll") for (int r_ = 0; r_ < 32; ++r_) buf[r_] =            \
          m[(size_t)(row0_ + r_) * 64];                                      \
    } else {                                                                 \
      _Pragma("unroll") for (int r_ = 0; r_ < 32; ++r_) buf[r_] = 0ull;      \
    }                                                                        \
  } while (0)

#define PROCH(buf, idx_)                                                     \
  do {                                                                       \
    int rb_ = (idx_) >> 1;                                                   \
    int bb_ = ((idx_)&1) * 32;                                               \
    u64 rm = remv, kb = 0;                                                   \
    _Pragma("unroll") for (int r_ = 0; r_ < 32; ++r_) {                      \
      u64 bit = 1ull << (bb_ + r_);                                          \
      bool kept = (rm & bit) == 0ull;                                        \
      if (kept) {                                                            \
        kb |= bit;                                                           \
        rm |= buf[r_];                                                       \
      }                                                                      \
    }                                                                        \
    kb = (u64)__shfl((long long)kb, rb_);                                    \
    _Pragma("unroll") for (int r_ = 0; r_ < 32; ++r_) {                      \
      remv |= ((kb >> (bb_ + r_)) & 1ull) ? buf[r_] : 0ull;                  \
    }                                                                        \
    if (t == rb_) keepm |= kb;                                               \
    cnt += __popcll(kb);                                                     \
  } while (0)

  LOADH(bufA, 0);
  int done = 0;
  for (int hb = 0; hb < 128 && !done; hb += 2) {
    LOADH(bufB, hb + 1);
    PROCH(bufA, hb);
    if (cnt >= POST) done = 1;
    if (!done) {
      LOADH(bufA, hb + 2);
      PROCH(bufB, hb + 1);
      if (cnt >= POST) done = 1;
    }
  }
#undef LOADH
#undef PROCH

  // rank among kept, then write output directly
  int nk = __popcll(keepm);
  int inc = nk;
#pragma unroll
  for (int off = 1; off < 64; off <<= 1) {
    int v = __shfl_up(inc, off);
    if (t >= off) inc += v;
  }
  int base = inc - nk;

  const float4* tbb = tb + (size_t)b * PRE;
  const float* ssb = sscore + (size_t)b * PRE;
  float4* outb = (float4*)out + (size_t)b * POST;
  float* outs = out + (size_t)B_ * POST * 4 + (size_t)b * POST;

  int r = base;
  for (int bit = 0; bit < 64; ++bit) {
    if ((keepm >> bit) & 1ull) {
      if (r < POST) {
        int i = t * 64 + bit;
        float4 v = tbb[i];
        float4 bx;
        bx.x = fminf(fmaxf(v.x, 0.f), 1.f);
        bx.y = fminf(fmaxf(v.y, 0.f), 1.f);
        bx.z = fminf(fmaxf(v.z, 0.f), 1.f);
        bx.w = fminf(fmaxf(v.w, 0.f), 1.f);
        outb[r] = bx;
        outs[r] = ssb[i];
      }
      ++r;
    }
  }
  int ntot = cnt < POST ? cnt : POST;
  for (int s = ntot + t; s < POST; s += 64) {
    outb[s] = make_float4(0.f, 0.f, 0.f, 0.f);
    outs[s] = 0.f;
  }
}

extern "C" void kernel_launch(void* const* d_in, const int* in_sizes, int n_in,
                              void* d_out, int out_size, void* d_ws,
                              size_t ws_size, hipStream_t stream) {
  const float* boxes = (const float*)d_in[0];   // [16,200000,4]
  const float* scores = (const float*)d_in[1];  // [16,200000,1]
  float* out = (float*)d_out;

  char* ws = (char*)d_ws;
  size_t off = 0;
  auto alloc = [&](size_t bytes) {
    size_t o = off;
    off = (off + bytes + 255) & ~(size_t)255;
    return o;
  };
  // zero-initialized region first (one memset)
  size_t o_hist1 = alloc((size_t)B_ * 4096 * 4);
  size_t o_hist2 = alloc((size_t)B_ * 4096 * 4);
  size_t o_hist3 = alloc((size_t)B_ * 256 * 4);
  size_t o_pref = alloc(B_ * 4);
  size_t o_K = alloc(B_ * 4);
  size_t o_cgt = alloc((size_t)B_ * CNT_PAD * 4);
  size_t o_ceq = alloc((size_t)B_ * CNT_PAD * 4);
  size_t zbytes = off;
  // non-zeroed scratch
  size_t o_sel = alloc((size_t)B_ * PRE * 8);
  size_t o_eq = alloc((size_t)B_ * PRE * 4);
  size_t o_sscore = alloc((size_t)B_ * PRE * 4);
  size_t o_tb = alloc((size_t)B_ * PRE * 16);
  size_t o_mask = alloc((size_t)B_ * PRE * 64 * 8);
  if (off > ws_size) return;  // workspace too small -> visible failure

  u32* hist1 = (u32*)(ws + o_hist1);
  u32* hist2 = (u32*)(ws + o_hist2);
  u32* hist3 = (u32*)(ws + o_hist3);
  u32* pref = (u32*)(ws + o_pref);
  u32* K = (u32*)(ws + o_K);
  u32* cgt = (u32*)(ws + o_cgt);
  u32* ceq = (u32*)(ws + o_ceq);
  u64* sel = (u64*)(ws + o_sel);
  u32* eqbuf = (u32*)(ws + o_eq);
  float* sscore = (float*)(ws + o_sscore);
  float4* tb = (float4*)(ws + o_tb);
  u64* mask = (u64*)(ws + o_mask);

  hipMemsetAsync(d_ws, 0, zbytes, stream);

  dim3 scanGrid(128, B_);
  k_hist1<<<scanGrid, 256, 0, stream>>>(scores, hist1);
  k_thresh<<<B_, 64, 0, stream>>>(hist1, 4096, 20, pref, K);
  k_hist2<<<scanGrid, 256, 0, stream>>>(scores, pref, hist2);
  k_thresh<<<B_, 64, 0, stream>>>(hist2, 4096, 8, pref, K);
  k_hist3<<<scanGrid, 256, 0, stream>>>(scores, pref, hist3);
  k_thresh<<<B_, 64, 0, stream>>>(hist3, 256, 0, pref, K);
  k_select<<<scanGrid, 256, 0, stream>>>(scores, pref, cgt, ceq, sel, eqbuf);
  k_sort<<<B_, 1024, 0, stream>>>(sel, eqbuf, pref, K, ceq,
                                  (const float4*)boxes, tb, sscore);
  k_mask<<<dim3(2080, B_), 64, 0, stream>>>(tb, mask);
  k_reduce<<<B_, 64, 0, stream>>>(mask, tb, sscore, out);
}